// Round 1
// baseline (350.759 us; speedup 1.0000x reference)
//
#include <hip/hip_runtime.h>

#define N_TOK 65536
#define DIM   256
#define K_CODES 1024
#define QUANT_OFF 16777216          // N_TOK*DIM
#define CB_OFF    16777216          // codebook copy starts here
#define PROBS_OFF (16777216 + 262144)
#define LOSS_OFF  (16777216 + 262144 + 1024)

typedef float  f32x4  __attribute__((ext_vector_type(4)));
typedef short  s16x8  __attribute__((ext_vector_type(8)));

__device__ __forceinline__ unsigned short f32_to_bf16(float x) {
    unsigned u = __float_as_uint(x);
    unsigned r = (u + 0x7FFFu + ((u >> 16) & 1u)) >> 16;
    return (unsigned short)r;
}

// ---------------- K0: codebook -> bf16 scratch, c2[k] = ||c_k||^2 ----------------
__global__ __launch_bounds__(256) void k_prep(const float* __restrict__ cb,
                                              float* __restrict__ c2,
                                              unsigned short* __restrict__ cbf) {
    const int k = blockIdx.x;
    const int t = threadIdx.x;
    float x = cb[k * DIM + t];
    cbf[k * DIM + t] = f32_to_bf16(x);
    float v = x * x;
    #pragma unroll
    for (int off = 32; off; off >>= 1) v += __shfl_down(v, off, 64);
    __shared__ float sred[4];
    const int lane = t & 63, wv = t >> 6;
    if (lane == 0) sred[wv] = v;
    __syncthreads();
    if (t == 0) c2[k] = sred[0] + sred[1] + sred[2] + sred[3];
}

// ---------------- K1: fused distances + argmin + softmax + gather + loss ----------------
// Block: 256 threads (4 waves). 32 tokens/block. Wave w owns codes [256w, 256w+256).
// Per-wave accumulators: 2 M-tiles x 16 N-tiles of mfma_f32_16x16x32_bf16 (128 VGPR).
__global__ __launch_bounds__(256, 2) void k_main(const float* __restrict__ z,
                                                 const float* __restrict__ cb,
                                                 const unsigned short* __restrict__ cbf,
                                                 const float* __restrict__ c2,
                                                 float* __restrict__ out_q,
                                                 float* __restrict__ probs_acc,
                                                 float* __restrict__ loss_acc) {
    const int t   = threadIdx.x;
    const int w   = t >> 6;       // wave 0..3
    const int ln  = t & 63;       // lane
    const int q   = ln >> 4;      // quad
    const int l15 = ln & 15;
    const int n0  = blockIdx.x * 32;
    const int k0  = w * 256;

    f32x4 acc[2][16];
    #pragma unroll
    for (int m = 0; m < 2; m++)
        #pragma unroll
        for (int nt = 0; nt < 16; nt++) { f32x4 zr = {0.f, 0.f, 0.f, 0.f}; acc[m][nt] = zr; }

    const unsigned short* bbase = cbf + (k0 + l15) * DIM + q * 8;

    // ---- K loop over d (8 steps of 32) ----
    #pragma unroll
    for (int ds = 0; ds < 8; ds++) {
        const int d0 = ds * 32;
        s16x8 afrag[2];
        #pragma unroll
        for (int m = 0; m < 2; m++) {
            const float* zp = z + (n0 + m * 16 + l15) * DIM + d0 + q * 8;
            f32x4 z0 = *(const f32x4*)(zp);
            f32x4 z1 = *(const f32x4*)(zp + 4);
            s16x8 a;
            a[0] = (short)f32_to_bf16(z0[0]); a[1] = (short)f32_to_bf16(z0[1]);
            a[2] = (short)f32_to_bf16(z0[2]); a[3] = (short)f32_to_bf16(z0[3]);
            a[4] = (short)f32_to_bf16(z1[0]); a[5] = (short)f32_to_bf16(z1[1]);
            a[6] = (short)f32_to_bf16(z1[2]); a[7] = (short)f32_to_bf16(z1[3]);
            afrag[m] = a;
        }
        #pragma unroll
        for (int nt = 0; nt < 16; nt++) {
            s16x8 b = *(const s16x8*)(bbase + nt * 16 * DIM + d0);
            acc[0][nt] = __builtin_amdgcn_mfma_f32_16x16x32_bf16(afrag[0], b, acc[0][nt], 0, 0, 0);
            acc[1][nt] = __builtin_amdgcn_mfma_f32_16x16x32_bf16(afrag[1], b, acc[1][nt], 0, 0, 0);
        }
    }

    // ---- epilogue pass 1: s = c2 - 2*dot; per-row local min/argmin/expsum; store e in acc ----
    float c2v[16];
    #pragma unroll
    for (int nt = 0; nt < 16; nt++) c2v[nt] = c2[k0 + nt * 16 + l15];

    float lmin[2][4], lesum[2][4]; int lidx[2][4];
    #pragma unroll
    for (int m = 0; m < 2; m++)
        #pragma unroll
        for (int v = 0; v < 4; v++) { lmin[m][v] = 3.4e38f; lidx[m][v] = 0x7fffffff; lesum[m][v] = 0.f; }

    #pragma unroll
    for (int m = 0; m < 2; m++)
        #pragma unroll
        for (int nt = 0; nt < 16; nt++) {
            const int col = k0 + nt * 16 + l15;
            #pragma unroll
            for (int v = 0; v < 4; v++) {
                float s = c2v[nt] - 2.0f * acc[m][nt][v];
                if (s < lmin[m][v]) { lmin[m][v] = s; lidx[m][v] = col; } // ascending col scan: ties keep lowest col
                float e = __expf(-s);
                acc[m][nt][v] = e;
                lesum[m][v] += e;
            }
        }

    // ---- cross-lane within quad (16 lanes hold one row's 256-code slice) ----
    #pragma unroll
    for (int off = 1; off < 16; off <<= 1) {
        #pragma unroll
        for (int m = 0; m < 2; m++)
            #pragma unroll
            for (int v = 0; v < 4; v++) {
                float omin = __shfl_xor(lmin[m][v], off, 64);
                int   oidx = __shfl_xor(lidx[m][v], off, 64);
                float oes  = __shfl_xor(lesum[m][v], off, 64);
                if (omin < lmin[m][v] || (omin == lmin[m][v] && oidx < lidx[m][v])) {
                    lmin[m][v] = omin; lidx[m][v] = oidx;
                }
                lesum[m][v] += oes;
            }
    }

    // ---- cross-wave combine through LDS ----
    __shared__ float redmin[4][32];
    __shared__ int   redidx[4][32];
    __shared__ float rede[4][32];
    __shared__ int   fidx[32];
    __shared__ float fU[32];
    if (l15 == 0) {
        #pragma unroll
        for (int m = 0; m < 2; m++)
            #pragma unroll
            for (int v = 0; v < 4; v++) {
                const int r = m * 16 + q * 4 + v;
                redmin[w][r] = lmin[m][v]; redidx[w][r] = lidx[m][v]; rede[w][r] = lesum[m][v];
            }
    }
    __syncthreads();
    if (t < 32) {
        float bm = redmin[0][t]; int bi = redidx[0][t];
        float U  = rede[0][t];
        #pragma unroll
        for (int ww = 1; ww < 4; ww++) {
            float m2 = redmin[ww][t]; int i2 = redidx[ww][t];
            if (m2 < bm || (m2 == bm && i2 < bi)) { bm = m2; bi = i2; }
            U += rede[ww][t];
        }
        fidx[t] = bi; fU[t] = U;
    }
    __syncthreads();

    // ---- probs: p = e / U, sum over the block's 32 rows, one atomic per code column ----
    float ps[16];
    #pragma unroll
    for (int nt = 0; nt < 16; nt++) ps[nt] = 0.f;
    #pragma unroll
    for (int m = 0; m < 2; m++)
        #pragma unroll
        for (int v = 0; v < 4; v++) {
            const float invU = 1.0f / fU[m * 16 + q * 4 + v];
            #pragma unroll
            for (int nt = 0; nt < 16; nt++) ps[nt] += acc[m][nt][v] * invU;
        }
    #pragma unroll
    for (int nt = 0; nt < 16; nt++) {
        ps[nt] += __shfl_xor(ps[nt], 16, 64);
        ps[nt] += __shfl_xor(ps[nt], 32, 64);
    }
    if (q == 0) {
        #pragma unroll
        for (int nt = 0; nt < 16; nt++)
            atomicAdd(&probs_acc[k0 + nt * 16 + l15], ps[nt]);
    }

    // ---- quantized gather + loss: wave w handles rows [8w, 8w+8) ----
    float lp = 0.f;
    #pragma unroll
    for (int i = 0; i < 8; i++) {
        const int r  = w * 8 + i;
        const int am = fidx[r];
        f32x4 qv = *(const f32x4*)(cb + am * DIM + ln * 4);
        f32x4 zv = *(const f32x4*)(z + (n0 + r) * DIM + ln * 4);
        *(f32x4*)(out_q + (n0 + r) * DIM + ln * 4) = qv;
        f32x4 dd = qv - zv;
        lp += dd[0] * dd[0] + dd[1] * dd[1] + dd[2] * dd[2] + dd[3] * dd[3];
    }
    #pragma unroll
    for (int off = 32; off; off >>= 1) lp += __shfl_down(lp, off, 64);
    if (ln == 0) atomicAdd(loss_acc, lp);
}

// ---------------- K2: codebook copy (overwrites bf16 scratch), probs mean+clip, vq_loss ----------------
__global__ __launch_bounds__(256) void k_fin(const float* __restrict__ cb,
                                             const float* __restrict__ probs_acc,
                                             const float* __restrict__ loss_acc,
                                             float* __restrict__ out) {
    const int g = blockIdx.x * 256 + threadIdx.x;   // 0 .. 262143
    out[CB_OFF + g] = cb[g];
    if (g < K_CODES) {
        float p = probs_acc[g] * (1.0f / 65536.0f);
        p = fminf(fmaxf(p, 0.001f), 0.999f);
        out[PROBS_OFF + g] = p;
    }
    if (g == 0) {
        // vq_loss = (1 + 0.25) * 1024 * sum_sq / (65536*256)
        out[LOSS_OFF] = loss_acc[0] * (1280.0f / 16777216.0f);
    }
}

extern "C" void kernel_launch(void* const* d_in, const int* in_sizes, int n_in,
                              void* d_out, int out_size, void* d_ws, size_t ws_size,
                              hipStream_t stream) {
    (void)in_sizes; (void)n_in; (void)out_size; (void)ws_size;
    const float* z  = (const float*)d_in[0];
    const float* cb = (const float*)d_in[1];
    float* out = (float*)d_out;

    float* c2        = (float*)d_ws;          // 1024 floats
    float* probs_acc = c2 + 1024;             // 1024 floats
    float* loss_acc  = probs_acc + 1024;      // 1 float

    // bf16 codebook scratch lives in d_out's codebook region; k_fin rewrites it with the fp32 copy.
    unsigned short* cbf = (unsigned short*)(out + CB_OFF);

    hipMemsetAsync(d_ws, 0, 2049 * sizeof(float), stream);
    k_prep<<<dim3(K_CODES), dim3(256), 0, stream>>>(cb, c2, cbf);
    k_main<<<dim3(N_TOK / 32), dim3(256), 0, stream>>>(z, cb, cbf, c2, out, probs_acc, loss_acc);
    k_fin<<<dim3(262144 / 256), dim3(256), 0, stream>>>(cb, probs_acc, loss_acc, out);
}